// Round 3
// baseline (320.998 us; speedup 1.0000x reference)
//
#include <hip/hip_runtime.h>
#include <math.h>

#define DIM 480          // 128*1 + 64*3 + 32*5
#define ROWS 8           // rows per tile
#define BLOCK 64         // one wave per block: no __syncthreads anywhere
#define NLOADS 15        // ROWS*DIM*4B / 1024B  (15 x 1KB global_load_lds)
#define TILE_F (ROWS * DIM)   // 3840 floats = 15360 B
#define NBLOCKS 1280     // 5 resident 30KB blocks/CU x 256 CU -> fully persistent

// scaling = silu(max(n,eps))/max(n,eps) == sigmoid(max(n,eps))
__device__ __forceinline__ float sig_of(float n) {
    n = fmaxf(n, 1e-8f);
    return __builtin_amdgcn_rcpf(1.0f + __expf(-n));
}

// Scale all groups of ROWS rows in-place in LDS.
// Bank analysis (32 banks, row stride 480 == 0 mod 32):
//   A: unit stride -> conflict-free; B: stride 3, C: stride 5 (gcd=1) -> <=2-way (free)
template <int R>
__device__ __forceinline__ void scale_groups(float* sbuf, int lane) {
    #pragma unroll
    for (int k = 0; k < R * 2; ++k) {            // region A: d=1, norm = |x|
        const int a = k * 64 + lane;
        float* p = sbuf + (a >> 7) * DIM + (a & 127);
        const float x = *p;
        *p = x * sig_of(fabsf(x));
    }
    #pragma unroll
    for (int k = 0; k < R; ++k) {                // region B: d=3
        const int b = k * 64 + lane;
        float* p = sbuf + (b >> 6) * DIM + 128 + 3 * (b & 63);
        const float x0 = p[0], x1 = p[1], x2 = p[2];
        const float s = sig_of(sqrtf(x0*x0 + x1*x1 + x2*x2));
        p[0] = x0 * s; p[1] = x1 * s; p[2] = x2 * s;
    }
    #pragma unroll
    for (int k = 0; k < R / 2; ++k) {            // region C: d=5
        const int c = k * 64 + lane;
        float* p = sbuf + (c >> 5) * DIM + 320 + 5 * (c & 31);
        const float x0 = p[0], x1 = p[1], x2 = p[2], x3 = p[3], x4 = p[4];
        const float s = sig_of(sqrtf(x0*x0 + x1*x1 + x2*x2 + x3*x3 + x4*x4));
        p[0] = x0*s; p[1] = x1*s; p[2] = x2*s; p[3] = x3*s; p[4] = x4*s;
    }
}

__device__ void scale_groups_rt(float* sbuf, int lane, int rows) {
    for (int a = lane; a < rows * 128; a += 64) {
        float* p = sbuf + (a >> 7) * DIM + (a & 127);
        const float x = *p;
        *p = x * sig_of(fabsf(x));
    }
    for (int b = lane; b < rows * 64; b += 64) {
        float* p = sbuf + (b >> 6) * DIM + 128 + 3 * (b & 63);
        const float x0 = p[0], x1 = p[1], x2 = p[2];
        const float s = sig_of(sqrtf(x0*x0 + x1*x1 + x2*x2));
        p[0] = x0 * s; p[1] = x1 * s; p[2] = x2 * s;
    }
    for (int c = lane; c < rows * 32; c += 64) {
        float* p = sbuf + (c >> 5) * DIM + 320 + 5 * (c & 31);
        const float x0 = p[0], x1 = p[1], x2 = p[2], x3 = p[3], x4 = p[4];
        const float s = sig_of(sqrtf(x0*x0 + x1*x1 + x2*x2 + x3*x3 + x4*x4));
        p[0] = x0*s; p[1] = x1*s; p[2] = x2*s; p[3] = x3*s; p[4] = x4*s;
    }
}

__device__ __forceinline__ void stage_tile(const float* gsrc, float* dst, int lane) {
    #pragma unroll
    for (int k = 0; k < NLOADS; ++k) {
        const float* gp = gsrc + (size_t)(k * 64 + lane) * 4;   // per-lane 16B
        __builtin_amdgcn_global_load_lds(
            (const __attribute__((address_space(1))) void*)gp,
            (__attribute__((address_space(3))) void*)((char*)dst + k * 1024),
            16, 0, 0);
    }
}

__global__ __launch_bounds__(BLOCK) void norm_act_kernel(
    const float* __restrict__ in, float* __restrict__ out, int n_rows, int ntiles)
{
    __shared__ __align__(16) float sbuf[2 * TILE_F];   // 30720 B -> 5 blocks/CU
    const int lane   = threadIdx.x;
    const int stride = gridDim.x;
    int t = blockIdx.x;
    if (t >= ntiles) return;

    int cur = 0;
    // ---- prologue: stage first tile into buffer 0 ----
    if (t * ROWS + ROWS <= n_rows)
        stage_tile(in + (size_t)t * TILE_F, sbuf, lane);

    for (; t < ntiles; t += stride) {
        const int row0 = t * ROWS;
        const int rows = min(ROWS, n_rows - row0);
        float* buf = sbuf + cur * TILE_F;

        if (rows == ROWS) {
            const int nt = t + stride;
            if (nt < ntiles && nt * ROWS + ROWS <= n_rows) {
                // issue next tile's loads FIRST, then counted wait:
                // FIFO drains tile-t loads + tile-(t-1) stores, keeps the
                // 15 newest (tile-nt loads) in flight across compute+store.
                stage_tile(in + (size_t)nt * TILE_F, sbuf + (cur ^ 1) * TILE_F, lane);
                asm volatile("s_waitcnt vmcnt(15)" ::: "memory");
            } else {
                asm volatile("s_waitcnt vmcnt(0)" ::: "memory");
            }

            scale_groups<ROWS>(buf, lane);      // in-place in LDS

            float* gdst = out + (size_t)row0 * DIM;
            #pragma unroll
            for (int k = 0; k < NLOADS; ++k) {  // ds_read_b128 -> store_dwordx4
                const int v = k * 64 + lane;
                ((float4*)gdst)[v] = ((const float4*)buf)[v];
            }
        } else if (rows > 0) {
            // partial tail tile (not hit for n_rows=100000): plain path
            asm volatile("s_waitcnt vmcnt(0)" ::: "memory");
            const float* gsrc = in + (size_t)row0 * DIM;
            for (int v = lane; v < rows * (DIM / 4); v += BLOCK)
                ((float4*)buf)[v] = ((const float4*)gsrc)[v];
            scale_groups_rt(buf, lane, rows);
            float* gdst = out + (size_t)row0 * DIM;
            for (int v = lane; v < rows * (DIM / 4); v += BLOCK)
                ((float4*)gdst)[v] = ((const float4*)buf)[v];
        }
        cur ^= 1;
    }
}

extern "C" void kernel_launch(void* const* d_in, const int* in_sizes, int n_in,
                              void* d_out, int out_size, void* d_ws, size_t ws_size,
                              hipStream_t stream) {
    const float* in  = (const float*)d_in[0];
    float*       out = (float*)d_out;
    const int n_rows = in_sizes[0] / DIM;                    // 100000
    const int ntiles = (n_rows + ROWS - 1) / ROWS;           // 12500
    const int grid   = ntiles < NBLOCKS ? ntiles : NBLOCKS;  // persistent waves
    norm_act_kernel<<<grid, BLOCK, 0, stream>>>(in, out, n_rows, ntiles);
}